// Round 2
// baseline (335.080 us; speedup 1.0000x reference)
//
#include <hip/hip_runtime.h>
#include <math.h>

// OscillatoryAttention: B=2,S=2048,D=1024,H=16,dk=64. Inputs/outputs FP32
// (reference is jnp.float32; round-1 NaN diagnosed as bf16-misread of fp32).
// Internal compute bf16 MFMA (threshold = 2% of max|ref| ≈ 5.1e-3 abs).
// Pipeline: [cvt x] [transpose+cvt W] [phase cos/sin fp32] [QKV gemm bf16]
//           [flash attn bf16] [out gemm bf16 -> fp32]

#define S_LEN 2048
#define NHEADS 16

typedef __attribute__((ext_vector_type(8))) short short8;
typedef __attribute__((ext_vector_type(4))) float floatx4;
typedef __attribute__((ext_vector_type(4))) unsigned int uintx4;

__device__ inline float bf2f(unsigned short u) {
    union { unsigned int i; float f; } v; v.i = ((unsigned int)u) << 16; return v.f;
}
__device__ inline unsigned short f2bf(float f) {
    union { float f; unsigned int i; } v; v.f = f;
    unsigned int u = v.i;
    return (unsigned short)((u + 0x7fffu + ((u >> 16) & 1u)) >> 16);
}

// ---------------- x fp32 -> bf16, 4M elements ----------------------------------
__global__ __launch_bounds__(256) void cvt_x(
    const float* __restrict__ src, unsigned short* __restrict__ dst) {
    int i = (blockIdx.x * 256 + threadIdx.x) * 8;
    float4 a = *reinterpret_cast<const float4*>(src + i);
    float4 b = *reinterpret_cast<const float4*>(src + i + 4);
    short8 o;
    o[0] = (short)f2bf(a.x); o[1] = (short)f2bf(a.y);
    o[2] = (short)f2bf(a.z); o[3] = (short)f2bf(a.w);
    o[4] = (short)f2bf(b.x); o[5] = (short)f2bf(b.y);
    o[6] = (short)f2bf(b.z); o[7] = (short)f2bf(b.w);
    *reinterpret_cast<short8*>(dst + i) = o;
}

// ---------------- weight transpose+cvt: WT[n][k] = bf16(W[k][n]), 1024x1024 ----
__global__ __launch_bounds__(256) void transpose4(
    const float* __restrict__ w0, const float* __restrict__ w1,
    const float* __restrict__ w2, const float* __restrict__ w3,
    unsigned short* __restrict__ d0, unsigned short* __restrict__ d1,
    unsigned short* __restrict__ d2, unsigned short* __restrict__ d3) {
    __shared__ __align__(16) unsigned short tile[64][72];
    int bid = blockIdx.x;
    int mat = bid >> 8;            // 4 matrices x 256 tiles
    int tl  = bid & 255;
    int tr = tl >> 4, tc = tl & 15;
    const float* src    = (mat == 0) ? w0 : (mat == 1) ? w1 : (mat == 2) ? w2 : w3;
    unsigned short* dst = (mat == 0) ? d0 : (mat == 1) ? d1 : (mat == 2) ? d2 : d3;
    int t = threadIdx.x;
    int col = t & 63, rbase = (t >> 6) * 16;
#pragma unroll
    for (int i = 0; i < 16; i++) {
        int row = rbase + i;
        tile[row][col] = f2bf(src[(size_t)(tr * 64 + row) * 1024 + tc * 64 + col]);
    }
    __syncthreads();
#pragma unroll
    for (int i = 0; i < 16; i++) {
        int row = rbase + i;
        dst[(size_t)(tc * 64 + row) * 1024 + tr * 64 + col] = tile[col][row];
    }
}

// ---------------- phase: phi[b][s][h] = x@Wp + bp (fp32); cos/sin at [b][h][s] -
__global__ __launch_bounds__(256) void phase_kernel(
    const float* __restrict__ x, const float* __restrict__ Wp,
    const float* __restrict__ bp,
    float* __restrict__ cosP, float* __restrict__ sinP) {
    __shared__ float red[256];
    int bid = blockIdx.x;                 // bid = b*2048 + s
    int b = bid >> 11, s = bid & 2047;
    int t = threadIdx.x;
    int h = t & 15, c = t >> 4;           // 16 k-chunks of 64
    const float* xr = x + (size_t)bid * 1024;
    float acc = 0.f;
#pragma unroll 8
    for (int kk = 0; kk < 64; kk++) {
        int k = c * 64 + kk;
        acc += xr[k] * Wp[k * 16 + h];
    }
    red[t] = acc;
    __syncthreads();
    if (t < 16) {
        float sum = 0.f;
#pragma unroll
        for (int c2 = 0; c2 < 16; c2++) sum += red[c2 * 16 + t];
        sum += bp[t];
        float sv, cv;
        __sincosf(sum, &sv, &cv);
        size_t o = ((size_t)b * NHEADS + t) * S_LEN + s;
        cosP[o] = cv; sinP[o] = sv;
    }
}

// ---------------- GEMM: C[M=4096][N] = A[4096][1024] @ BT[N][1024]^T (bf16) ----
// mode 0: row-major fp32 out (+bias b0) -> of
// mode 1: N=3072 QKV; bf16 out layout (B,H,S,dk); Q scaled by 0.125 after bias.
__global__ __launch_bounds__(256) void gemm_bt(
    const unsigned short* __restrict__ A, const unsigned short* __restrict__ BT,
    int N, int mode,
    const float* __restrict__ b0, const float* __restrict__ b1,
    const float* __restrict__ b2,
    unsigned short* __restrict__ o0, unsigned short* __restrict__ o1,
    unsigned short* __restrict__ o2, float* __restrict__ of) {
    __shared__ __align__(16) unsigned short As[128][40];   // +8 pad, row=80B (16B mult)
    __shared__ __align__(16) unsigned short Bs[128][40];
    const int K = 1024;
    int t = threadIdx.x;
    int mBase = blockIdx.x * 128;
    int nBase = blockIdx.y * 128;
    int w = t >> 6, lane = t & 63, l15 = lane & 15, quad = lane >> 4;
    int wm = (w & 1) * 64, wn = (w >> 1) * 64;
    floatx4 acc[4][4];
#pragma unroll
    for (int i = 0; i < 4; i++)
#pragma unroll
        for (int j = 0; j < 4; j++) acc[i][j] = (floatx4){0.f, 0.f, 0.f, 0.f};

    int srow = t >> 2, sseg = t & 3;
    for (int k0 = 0; k0 < K; k0 += 32) {
        __syncthreads();
#pragma unroll
        for (int i = 0; i < 2; i++) {
            int row = srow + i * 64;
            short8 av = *reinterpret_cast<const short8*>(&A[(size_t)(mBase + row) * K + k0 + sseg * 8]);
            *reinterpret_cast<short8*>(&As[row][sseg * 8]) = av;
            short8 bv = *reinterpret_cast<const short8*>(&BT[(size_t)(nBase + row) * K + k0 + sseg * 8]);
            *reinterpret_cast<short8*>(&Bs[row][sseg * 8]) = bv;
        }
        __syncthreads();
        short8 af[4], bf[4];
#pragma unroll
        for (int mi = 0; mi < 4; mi++)
            af[mi] = *reinterpret_cast<const short8*>(&As[wm + mi * 16 + l15][quad * 8]);
#pragma unroll
        for (int ni = 0; ni < 4; ni++)
            bf[ni] = *reinterpret_cast<const short8*>(&Bs[wn + ni * 16 + l15][quad * 8]);
#pragma unroll
        for (int mi = 0; mi < 4; mi++)
#pragma unroll
            for (int ni = 0; ni < 4; ni++)
                acc[mi][ni] = __builtin_amdgcn_mfma_f32_16x16x32_bf16(af[mi], bf[ni], acc[mi][ni], 0, 0, 0);
    }

#pragma unroll
    for (int mi = 0; mi < 4; mi++) {
        int rowB = mBase + wm + mi * 16 + quad * 4;
#pragma unroll
        for (int ni = 0; ni < 4; ni++) {
            int col = nBase + wn + ni * 16 + l15;
            if (mode == 0) {
                float bias = b0[col];
#pragma unroll
                for (int r = 0; r < 4; r++) {
                    of[(size_t)(rowB + r) * N + col] = acc[mi][ni][r] + bias;
                }
            } else {
                int mat = col >> 10, nn = col & 1023;
                int h = nn >> 6, d = nn & 63;
                const float* bias  = (mat == 0) ? b0 : (mat == 1) ? b1 : b2;
                unsigned short* op = (mat == 0) ? o0 : (mat == 1) ? o1 : o2;
                float bv = bias[nn];
                float scl = (mat == 0) ? 0.125f : 1.0f;   // fold dk^-0.5 into Q
#pragma unroll
                for (int r = 0; r < 4; r++) {
                    int m = rowB + r;
                    int b = m >> 11, sidx = m & 2047;
                    float cv = (acc[mi][ni][r] + bv) * scl;
                    op[(((size_t)b * NHEADS + h) * S_LEN + sidx) * 64 + d] = f2bf(cv);
                }
            }
        }
    }
}

// ---------------- flash attention with oscillatory coherence --------------------
// grid = B*H*(S/64) = 1024 blocks, 256 thr (4 waves x 16 Q-rows).
// coherence: alpha*cos(pi-pj) = (alpha*ci)*cj + (alpha*si)*sj  (rank-2, no cos in loop)
__global__ __launch_bounds__(256) void attn_kernel(
    const unsigned short* __restrict__ Qg, const unsigned short* __restrict__ Kg,
    const unsigned short* __restrict__ Vg,
    const float* __restrict__ cosP, const float* __restrict__ sinP,
    const float* __restrict__ alpha, unsigned short* __restrict__ ctx) {
    __shared__ __align__(16) unsigned short Ks[64][72];     // row = 144B
    __shared__ __align__(16) unsigned short Vs[64][66];     // row = 132B
    __shared__ __align__(16) unsigned short Pl[4][16][72];  // per-wave P (C->A layout)
    __shared__ float cjs[64], sjs[64];

    int bid = blockIdx.x;
    int bh = bid >> 5;          // b*16 + h
    int qt = bid & 31;
    int t = threadIdx.x, w = t >> 6, lane = t & 63, l15 = lane & 15, quad = lane >> 4;
    int m0 = qt * 64 + w * 16;
    size_t baseBH = (size_t)bh * S_LEN * 64;

    // Q fragments (A-layout), Q already has 0.125 scale folded
    short8 qf[2];
#pragma unroll
    for (int c = 0; c < 2; c++)
        qf[c] = *reinterpret_cast<const short8*>(&Qg[baseBH + (size_t)(m0 + l15) * 64 + c * 32 + quad * 8]);

    float alph = alpha[bh & 15];
    float ci[4], si[4];
#pragma unroll
    for (int r = 0; r < 4; r++) {
        size_t o = (size_t)bh * S_LEN + m0 + quad * 4 + r;
        ci[r] = alph * cosP[o];
        si[r] = alph * sinP[o];
    }

    float mi_[4], li[4];
    floatx4 oacc[4];
#pragma unroll
    for (int r = 0; r < 4; r++) { mi_[r] = -1e30f; li[r] = 0.f; }
#pragma unroll
    for (int tt = 0; tt < 4; tt++) oacc[tt] = (floatx4){0.f, 0.f, 0.f, 0.f};

    for (int kt = 0; kt < 32; kt++) {
        __syncthreads();
        {   // stage K (row-major) and V (row-major, stride 66) + cos/sin of j
            int r8 = t >> 3, seg = t & 7;
#pragma unroll
            for (int i = 0; i < 2; i++) {
                int j = r8 + i * 32;
                short8 kv = *reinterpret_cast<const short8*>(&Kg[baseBH + (size_t)(kt * 64 + j) * 64 + seg * 8]);
                *reinterpret_cast<short8*>(&Ks[j][seg * 8]) = kv;
                uintx4 vv = *reinterpret_cast<const uintx4*>(&Vg[baseBH + (size_t)(kt * 64 + j) * 64 + seg * 8]);
#pragma unroll
                for (int u = 0; u < 4; u++)
                    *reinterpret_cast<unsigned int*>(&Vs[j][seg * 8 + 2 * u]) = vv[u];
            }
            if (t < 64)        cjs[t]      = cosP[(size_t)bh * S_LEN + kt * 64 + t];
            else if (t < 128)  sjs[t - 64] = sinP[(size_t)bh * S_LEN + kt * 64 + (t - 64)];
        }
        __syncthreads();

        // scores for 4 16-col subtiles
        floatx4 sfr[4];
        float tm[4] = {-1e30f, -1e30f, -1e30f, -1e30f};
#pragma unroll
        for (int t16 = 0; t16 < 4; t16++) {
            short8 kf0 = *reinterpret_cast<const short8*>(&Ks[t16 * 16 + l15][quad * 8]);
            short8 kf1 = *reinterpret_cast<const short8*>(&Ks[t16 * 16 + l15][32 + quad * 8]);
            floatx4 sacc = (floatx4){0.f, 0.f, 0.f, 0.f};
            sacc = __builtin_amdgcn_mfma_f32_16x16x32_bf16(qf[0], kf0, sacc, 0, 0, 0);
            sacc = __builtin_amdgcn_mfma_f32_16x16x32_bf16(qf[1], kf1, sacc, 0, 0, 0);
            float cj = cjs[t16 * 16 + l15], sj = sjs[t16 * 16 + l15];
#pragma unroll
            for (int r = 0; r < 4; r++) {
                float v = sacc[r] + ci[r] * cj + si[r] * sj;
                sacc[r] = v;
                tm[r] = fmaxf(tm[r], v);
            }
            sfr[t16] = sacc;
        }
        // row max over the 16 lanes holding this row
#pragma unroll
        for (int r = 0; r < 4; r++) {
            float v = tm[r];
            v = fmaxf(v, __shfl_xor(v, 1));
            v = fmaxf(v, __shfl_xor(v, 2));
            v = fmaxf(v, __shfl_xor(v, 4));
            v = fmaxf(v, __shfl_xor(v, 8));
            tm[r] = v;
        }
        float alpha_r[4], psum[4];
#pragma unroll
        for (int r = 0; r < 4; r++) {
            float mnew = fmaxf(mi_[r], tm[r]);
            alpha_r[r] = __expf(mi_[r] - mnew);
            mi_[r] = mnew;
            psum[r] = 0.f;
        }
#pragma unroll
        for (int t16 = 0; t16 < 4; t16++)
#pragma unroll
            for (int r = 0; r < 4; r++) {
                float p = __expf(sfr[t16][r] - mi_[r]);
                psum[r] += p;
                Pl[w][quad * 4 + r][t16 * 16 + l15] = f2bf(p);
            }
#pragma unroll
        for (int r = 0; r < 4; r++) {
            float v = psum[r];
            v += __shfl_xor(v, 1);
            v += __shfl_xor(v, 2);
            v += __shfl_xor(v, 4);
            v += __shfl_xor(v, 8);
            li[r] = li[r] * alpha_r[r] + v;
        }
#pragma unroll
        for (int tt = 0; tt < 4; tt++)
#pragma unroll
            for (int r = 0; r < 4; r++) oacc[tt][r] *= alpha_r[r];

        // PV: O(16x64) += P(16x64) @ V(64x64)
#pragma unroll
        for (int c = 0; c < 2; c++) {
            short8 pf = *reinterpret_cast<const short8*>(&Pl[w][l15][c * 32 + quad * 8]);
#pragma unroll
            for (int tt = 0; tt < 4; tt++) {
                short8 vf;
#pragma unroll
                for (int jj = 0; jj < 8; jj++)
                    vf[jj] = (short)Vs[c * 32 + quad * 8 + jj][tt * 16 + l15];
                oacc[tt] = __builtin_amdgcn_mfma_f32_16x16x32_bf16(pf, vf, oacc[tt], 0, 0, 0);
            }
        }
    }

    // epilogue: ctx[b][s][h*64+d] bf16
    int b = bh >> 4, h = bh & 15;
#pragma unroll
    for (int tt = 0; tt < 4; tt++)
#pragma unroll
        for (int r = 0; r < 4; r++) {
            float v = oacc[tt][r] / li[r];
            int srow = m0 + quad * 4 + r;
            ctx[((size_t)(b * S_LEN + srow)) * 1024 + h * 64 + tt * 16 + l15] = f2bf(v);
        }
}

extern "C" void kernel_launch(void* const* d_in, const int* in_sizes, int n_in,
                              void* d_out, int out_size, void* d_ws, size_t ws_size,
                              hipStream_t stream) {
    const float* x     = (const float*)d_in[0];
    const float* Wq    = (const float*)d_in[1];
    const float* bq    = (const float*)d_in[2];
    const float* Wk    = (const float*)d_in[3];
    const float* bk    = (const float*)d_in[4];
    const float* Wv    = (const float*)d_in[5];
    const float* bv    = (const float*)d_in[6];
    const float* Wo    = (const float*)d_in[7];
    const float* bo    = (const float*)d_in[8];
    const float* Wp    = (const float*)d_in[9];
    const float* bp    = (const float*)d_in[10];
    const float* alpha = (const float*)d_in[11];
    float* out = (float*)d_out;

    const size_t MB = 1048576;
    char* ws = (char*)d_ws;
    unsigned short* WT   = (unsigned short*)(ws);             // 3072x1024 bf16
    unsigned short* WoT  = (unsigned short*)(ws + 6 * MB);    // 1024x1024 bf16
    unsigned short* xb   = (unsigned short*)(ws + 8 * MB);    // (B,S,D) bf16
    unsigned short* ctx  = (unsigned short*)(ws + 8 * MB);    // aliases xb (dead after QKV gemm)
    unsigned short* Qw   = (unsigned short*)(ws + 16 * MB);   // (B,H,S,dk) bf16, pre-scaled
    unsigned short* Kw   = (unsigned short*)(ws + 24 * MB);
    unsigned short* Vw   = (unsigned short*)(ws + 32 * MB);
    float* cosP          = (float*)(ws + 40 * MB);            // (B,H,S) fp32
    float* sinP          = (float*)(ws + 40 * MB + 262144);

    hipLaunchKernelGGL(cvt_x, dim3(2048), dim3(256), 0, stream, x, xb);
    hipLaunchKernelGGL(transpose4, dim3(1024), dim3(256), 0, stream,
                       Wq, Wk, Wv, Wo, WT, WT + 1048576, WT + 2097152, WoT);
    hipLaunchKernelGGL(phase_kernel, dim3(4096), dim3(256), 0, stream,
                       x, Wp, bp, cosP, sinP);
    hipLaunchKernelGGL(gemm_bt, dim3(32, 24), dim3(256), 0, stream,
                       xb, WT, 3072, 1, bq, bk, bv, Qw, Kw, Vw, (float*)nullptr);
    hipLaunchKernelGGL(attn_kernel, dim3(1024), dim3(256), 0, stream,
                       Qw, Kw, Vw, cosP, sinP, alpha, ctx);
    hipLaunchKernelGGL(gemm_bt, dim3(32, 8), dim3(256), 0, stream,
                       ctx, WoT, 1024, 0, bo, bo, bo,
                       (unsigned short*)nullptr, (unsigned short*)nullptr,
                       (unsigned short*)nullptr, out);
}

// Round 3
// 264.730 us; speedup vs baseline: 1.2657x; 1.2657x over previous
//
#include <hip/hip_runtime.h>
#include <math.h>

// OscillatoryAttention: B=2,S=2048,D=1024,H=16,dk=64. FP32 in/out, bf16 MFMA inside.
// R3: attention rewritten — pre-transposed V (written by GEMM epilogue), no online
// max (exp2 direct, log2e folded into Q-scale and ci/si), row-sums via MFMA
// ones-row, P packed to bf16 with v_perm, 32 Q-rows/wave. All LDS b128 bank-clean.

#define S_LEN 2048
#define NHEADS 16

typedef __attribute__((ext_vector_type(8))) short short8;
typedef __attribute__((ext_vector_type(4))) float floatx4;
typedef __attribute__((ext_vector_type(4))) unsigned int uintx4;

__device__ inline float bf2f(unsigned short u) {
    union { unsigned int i; float f; } v; v.i = ((unsigned int)u) << 16; return v.f;
}
__device__ inline unsigned short f2bf(float f) {
    union { float f; unsigned int i; } v; v.f = f;
    unsigned int u = v.i;
    return (unsigned short)((u + 0x7fffu + ((u >> 16) & 1u)) >> 16);
}
// pack two f32 -> packed bf16 u32 (truncation; bias cancels in softmax ratio)
__device__ inline unsigned int pack2_bf16(float hi, float lo) {
    union { float f; unsigned int u; } a, b; a.f = hi; b.f = lo;
    return __builtin_amdgcn_perm(a.u, b.u, 0x07060302u);
}

// ---------------- x fp32 -> bf16 ------------------------------------------------
__global__ __launch_bounds__(256) void cvt_x(
    const float* __restrict__ src, unsigned short* __restrict__ dst) {
    int i = (blockIdx.x * 256 + threadIdx.x) * 8;
    float4 a = *reinterpret_cast<const float4*>(src + i);
    float4 b = *reinterpret_cast<const float4*>(src + i + 4);
    short8 o;
    o[0] = (short)f2bf(a.x); o[1] = (short)f2bf(a.y);
    o[2] = (short)f2bf(a.z); o[3] = (short)f2bf(a.w);
    o[4] = (short)f2bf(b.x); o[5] = (short)f2bf(b.y);
    o[6] = (short)f2bf(b.z); o[7] = (short)f2bf(b.w);
    *reinterpret_cast<short8*>(dst + i) = o;
}

// ---------------- weight transpose+cvt: WT[n][k] = bf16(W[k][n]) ----------------
__global__ __launch_bounds__(256) void transpose4(
    const float* __restrict__ w0, const float* __restrict__ w1,
    const float* __restrict__ w2, const float* __restrict__ w3,
    unsigned short* __restrict__ d0, unsigned short* __restrict__ d1,
    unsigned short* __restrict__ d2, unsigned short* __restrict__ d3) {
    __shared__ __align__(16) unsigned short tile[64][72];
    int bid = blockIdx.x;
    int mat = bid >> 8;
    int tl  = bid & 255;
    int tr = tl >> 4, tc = tl & 15;
    const float* src    = (mat == 0) ? w0 : (mat == 1) ? w1 : (mat == 2) ? w2 : w3;
    unsigned short* dst = (mat == 0) ? d0 : (mat == 1) ? d1 : (mat == 2) ? d2 : d3;
    int t = threadIdx.x;
    int col = t & 63, rbase = (t >> 6) * 16;
#pragma unroll
    for (int i = 0; i < 16; i++) {
        int row = rbase + i;
        tile[row][col] = f2bf(src[(size_t)(tr * 64 + row) * 1024 + tc * 64 + col]);
    }
    __syncthreads();
#pragma unroll
    for (int i = 0; i < 16; i++) {
        int row = rbase + i;
        dst[(size_t)(tc * 64 + row) * 1024 + tr * 64 + col] = tile[col][row];
    }
}

// ---------------- phase: phi = x@Wp + bp (fp32); cos/sin at [b][h][s] -----------
__global__ __launch_bounds__(256) void phase_kernel(
    const float* __restrict__ x, const float* __restrict__ Wp,
    const float* __restrict__ bp,
    float* __restrict__ cosP, float* __restrict__ sinP) {
    __shared__ float red[256];
    int bid = blockIdx.x;
    int b = bid >> 11, s = bid & 2047;
    int t = threadIdx.x;
    int h = t & 15, c = t >> 4;
    const float* xr = x + (size_t)bid * 1024;
    float acc = 0.f;
#pragma unroll 8
    for (int kk = 0; kk < 64; kk++) {
        int k = c * 64 + kk;
        acc += xr[k] * Wp[k * 16 + h];
    }
    red[t] = acc;
    __syncthreads();
    if (t < 16) {
        float sum = 0.f;
#pragma unroll
        for (int c2 = 0; c2 < 16; c2++) sum += red[c2 * 16 + t];
        sum += bp[t];
        float sv, cv;
        __sincosf(sum, &sv, &cv);
        size_t o = ((size_t)b * NHEADS + t) * S_LEN + s;
        cosP[o] = cv; sinP[o] = sv;
    }
}

// ---------------- GEMM: C[4096][N] = A[4096][1024] @ BT[N][1024]^T (bf16) -------
// mode 0: row-major fp32 out (+bias) -> of
// mode 1: N=3072 QKV: Q->(B,H,S,dk) scaled by 0.125*log2e; K->(B,H,S,dk);
//         V->TRANSPOSED (B,H,dk,S) via packed dwordx2 stores.
__global__ __launch_bounds__(256) void gemm_bt(
    const unsigned short* __restrict__ A, const unsigned short* __restrict__ BT,
    int N, int mode,
    const float* __restrict__ b0, const float* __restrict__ b1,
    const float* __restrict__ b2,
    unsigned short* __restrict__ o0, unsigned short* __restrict__ o1,
    unsigned short* __restrict__ o2, float* __restrict__ of) {
    __shared__ __align__(16) unsigned short As[128][40];
    __shared__ __align__(16) unsigned short Bs[128][40];
    const int K = 1024;
    int t = threadIdx.x;
    int mBase = blockIdx.x * 128;
    int nBase = blockIdx.y * 128;
    int w = t >> 6, lane = t & 63, l15 = lane & 15, quad = lane >> 4;
    int wm = (w & 1) * 64, wn = (w >> 1) * 64;
    floatx4 acc[4][4];
#pragma unroll
    for (int i = 0; i < 4; i++)
#pragma unroll
        for (int j = 0; j < 4; j++) acc[i][j] = (floatx4){0.f, 0.f, 0.f, 0.f};

    int srow = t >> 2, sseg = t & 3;
    for (int k0 = 0; k0 < K; k0 += 32) {
        __syncthreads();
#pragma unroll
        for (int i = 0; i < 2; i++) {
            int row = srow + i * 64;
            short8 av = *reinterpret_cast<const short8*>(&A[(size_t)(mBase + row) * K + k0 + sseg * 8]);
            *reinterpret_cast<short8*>(&As[row][sseg * 8]) = av;
            short8 bv = *reinterpret_cast<const short8*>(&BT[(size_t)(nBase + row) * K + k0 + sseg * 8]);
            *reinterpret_cast<short8*>(&Bs[row][sseg * 8]) = bv;
        }
        __syncthreads();
        short8 af[4], bfr[4];
#pragma unroll
        for (int mi = 0; mi < 4; mi++)
            af[mi] = *reinterpret_cast<const short8*>(&As[wm + mi * 16 + l15][quad * 8]);
#pragma unroll
        for (int ni = 0; ni < 4; ni++)
            bfr[ni] = *reinterpret_cast<const short8*>(&Bs[wn + ni * 16 + l15][quad * 8]);
#pragma unroll
        for (int mi = 0; mi < 4; mi++)
#pragma unroll
            for (int ni = 0; ni < 4; ni++)
                acc[mi][ni] = __builtin_amdgcn_mfma_f32_16x16x32_bf16(af[mi], bfr[ni], acc[mi][ni], 0, 0, 0);
    }

#pragma unroll
    for (int mi = 0; mi < 4; mi++) {
        int rowB = mBase + wm + mi * 16 + quad * 4;
#pragma unroll
        for (int ni = 0; ni < 4; ni++) {
            int col = nBase + wn + ni * 16 + l15;
            if (mode == 0) {
                float bias = b0[col];
#pragma unroll
                for (int r = 0; r < 4; r++) {
                    of[(size_t)(rowB + r) * N + col] = acc[mi][ni][r] + bias;
                }
            } else {
                int mat = col >> 10, nn = col & 1023;
                int h = nn >> 6, d = nn & 63;
                int b = rowB >> 11, sidx = rowB & 2047;
                if (mat == 2) {
                    float bv = b2[nn];
                    unsigned int lo = (unsigned int)f2bf(acc[mi][ni][0] + bv) |
                                      ((unsigned int)f2bf(acc[mi][ni][1] + bv) << 16);
                    unsigned int hi = (unsigned int)f2bf(acc[mi][ni][2] + bv) |
                                      ((unsigned int)f2bf(acc[mi][ni][3] + bv) << 16);
                    *reinterpret_cast<uint2*>(
                        &o2[((size_t)((b * NHEADS + h) * 64 + d)) * S_LEN + sidx]) =
                        make_uint2(lo, hi);
                } else {
                    const float* bias  = (mat == 0) ? b0 : b1;
                    unsigned short* op = (mat == 0) ? o0 : o1;
                    float bv = bias[nn];
                    float scl = (mat == 0) ? 0.18033688f : 1.0f;  // dk^-0.5 * log2e folded into Q
#pragma unroll
                    for (int r = 0; r < 4; r++) {
                        float cv = (acc[mi][ni][r] + bv) * scl;
                        op[(((size_t)b * NHEADS + h) * S_LEN + (sidx + r)) * 64 + d] = f2bf(cv);
                    }
                }
            }
        }
    }
}

// ---------------- flash attention, oscillatory coherence ------------------------
// grid = B*H*(S/128) = 512 blocks, 256 thr (4 waves x 32 Q-rows).
// p = exp2(qk*0.125*L2E + ci*cj + si*sj), ci/si pre-scaled by alpha*L2E.
// l = P@ones via MFMA ones-row (tt=4). P stored packed-bf16 with column order
// pi(j) = (j>>5)*32 + (j&15)*2 + ((j>>4)&1); V LDS rows use same order.
__global__ __launch_bounds__(256) void attn_kernel(
    const unsigned short* __restrict__ Qg, const unsigned short* __restrict__ Kg,
    const unsigned short* __restrict__ VTg,
    const float* __restrict__ cosP, const float* __restrict__ sinP,
    const float* __restrict__ alpha, unsigned short* __restrict__ ctx) {
    __shared__ __align__(16) unsigned short Ks[64][72];   // K rows (j), row-major
    __shared__ __align__(16) unsigned short Vt[80][72];   // rows d; cols pi(j); 64=ones,65..79=0
    __shared__ __align__(16) unsigned int  Plb[4][32][36];// per-wave packed-bf16 P
    __shared__ float cjs[64], sjs[64];

    int bid = blockIdx.x;
    int bh = bid >> 4, qt = bid & 15;
    int t = threadIdx.x, w = t >> 6, lane = t & 63, l15 = lane & 15, quad = lane >> 4;
    int m0w = qt * 128 + w * 32;
    size_t baseBH = (size_t)bh * (S_LEN * 64);
    const float L2E = 1.44269504f;

    // Q fragments (A-layout); Q pre-scaled by 0.125*L2E in GEMM
    short8 qf[2][2];
#pragma unroll
    for (int mi = 0; mi < 2; mi++)
#pragma unroll
        for (int c = 0; c < 2; c++)
            qf[mi][c] = *reinterpret_cast<const short8*>(
                &Qg[baseBH + (size_t)(m0w + mi * 16 + l15) * 64 + c * 32 + quad * 8]);

    float alph = alpha[bh & 15] * L2E;
    float ci[2][4], si[2][4];
#pragma unroll
    for (int mi = 0; mi < 2; mi++)
#pragma unroll
        for (int r = 0; r < 4; r++) {
            size_t o = (size_t)bh * S_LEN + m0w + mi * 16 + quad * 4 + r;
            ci[mi][r] = alph * cosP[o];
            si[mi][r] = alph * sinP[o];
        }

    // ones-row init (row 64 = 1.0bf16, rows 65..79 = 0); staging never touches these
    {
        int rr = 64 + (t >> 4), c4 = (t & 15) * 4;
        unsigned int v = (rr == 64) ? 0x3F803F80u : 0u;
        *reinterpret_cast<uint2*>(&Vt[rr][c4]) = make_uint2(v, v);
    }

    floatx4 oacc[2][5];
#pragma unroll
    for (int mi = 0; mi < 2; mi++)
#pragma unroll
        for (int tt = 0; tt < 5; tt++) oacc[mi][tt] = (floatx4){0.f, 0.f, 0.f, 0.f};

    int krow = t >> 3, kseg = t & 7;
    int vd = t >> 2, vq = t & 3;
    int vjbase = (vq >> 1) * 32 + (vq & 1) * 8;

    for (int kt = 0; kt < 32; kt++) {
        __syncthreads();
        // stage K (row-major)
#pragma unroll
        for (int i = 0; i < 2; i++) {
            int j = krow + i * 32;
            short8 kv = *reinterpret_cast<const short8*>(
                &Kg[baseBH + (size_t)(kt * 64 + j) * 64 + kseg * 8]);
            *reinterpret_cast<short8*>(&Ks[j][kseg * 8]) = kv;
        }
        // stage V-transposed with pi-interleave: shorts (2s,2s+1) = (V[j],V[j+16])
        {
            const unsigned short* vr = &VTg[baseBH + (size_t)vd * S_LEN + kt * 64 + vjbase];
            uintx4 a = *reinterpret_cast<const uintx4*>(vr);
            uintx4 b = *reinterpret_cast<const uintx4*>(vr + 16);
            uintx4 o1, o2;
#pragma unroll
            for (int k = 0; k < 2; k++) {
                o1[2 * k]     = __builtin_amdgcn_perm(b[k], a[k], 0x05040100u);
                o1[2 * k + 1] = __builtin_amdgcn_perm(b[k], a[k], 0x07060302u);
                o2[2 * k]     = __builtin_amdgcn_perm(b[k + 2], a[k + 2], 0x05040100u);
                o2[2 * k + 1] = __builtin_amdgcn_perm(b[k + 2], a[k + 2], 0x07060302u);
            }
            *reinterpret_cast<uintx4*>(&Vt[vd][vq * 16]) = o1;
            *reinterpret_cast<uintx4*>(&Vt[vd][vq * 16 + 8]) = o2;
        }
        if (t < 64)       cjs[t]      = cosP[(size_t)bh * S_LEN + kt * 64 + t];
        else if (t < 128) sjs[t - 64] = sinP[(size_t)bh * S_LEN + kt * 64 + (t - 64)];
        __syncthreads();

        // QK^T: K-fragments shared across both m-tiles
        floatx4 sacc[2][4];
#pragma unroll
        for (int t16 = 0; t16 < 4; t16++) {
            short8 kf0 = *reinterpret_cast<const short8*>(&Ks[t16 * 16 + l15][quad * 8]);
            short8 kf1 = *reinterpret_cast<const short8*>(&Ks[t16 * 16 + l15][32 + quad * 8]);
#pragma unroll
            for (int mi = 0; mi < 2; mi++) {
                floatx4 s0 = (floatx4){0.f, 0.f, 0.f, 0.f};
                s0 = __builtin_amdgcn_mfma_f32_16x16x32_bf16(qf[mi][0], kf0, s0, 0, 0, 0);
                s0 = __builtin_amdgcn_mfma_f32_16x16x32_bf16(qf[mi][1], kf1, s0, 0, 0, 0);
                sacc[mi][t16] = s0;
            }
        }
        float cjv[4], sjv[4];
#pragma unroll
        for (int t16 = 0; t16 < 4; t16++) {
            cjv[t16] = cjs[t16 * 16 + l15];
            sjv[t16] = sjs[t16 * 16 + l15];
        }

        // p = exp2(s + coherence); pack pairs (t16: 0&1, 2&3) -> packed bf16
#pragma unroll
        for (int mi = 0; mi < 2; mi++) {
#pragma unroll
            for (int r = 0; r < 4; r++) {
                float cc = ci[mi][r], ss = si[mi][r];
                float p0 = __builtin_amdgcn_exp2f(sacc[mi][0][r] + cc * cjv[0] + ss * sjv[0]);
                float p1 = __builtin_amdgcn_exp2f(sacc[mi][1][r] + cc * cjv[1] + ss * sjv[1]);
                float p2 = __builtin_amdgcn_exp2f(sacc[mi][2][r] + cc * cjv[2] + ss * sjv[2]);
                float p3 = __builtin_amdgcn_exp2f(sacc[mi][3][r] + cc * cjv[3] + ss * sjv[3]);
                int row = mi * 16 + quad * 4 + r;
                Plb[w][row][l15]      = pack2_bf16(p1, p0);
                Plb[w][row][16 + l15] = pack2_bf16(p3, p2);
            }
        }

        // P A-fragments (contiguous b128 thanks to pi ordering)
        short8 pf[2][2];
#pragma unroll
        for (int mi = 0; mi < 2; mi++)
#pragma unroll
            for (int c = 0; c < 2; c++)
                pf[mi][c] = *reinterpret_cast<const short8*>(
                    reinterpret_cast<const unsigned short*>(&Plb[w][0][0]) +
                    (mi * 16 + l15) * 72 + c * 32 + quad * 8);

        // PV (+ ones-row tt=4 accumulates row-sums l)
#pragma unroll
        for (int c = 0; c < 2; c++) {
#pragma unroll
            for (int tt = 0; tt < 5; tt++) {
                short8 vf = *reinterpret_cast<const short8*>(&Vt[tt * 16 + l15][c * 32 + quad * 8]);
                oacc[0][tt] = __builtin_amdgcn_mfma_f32_16x16x32_bf16(pf[0][c], vf, oacc[0][tt], 0, 0, 0);
                oacc[1][tt] = __builtin_amdgcn_mfma_f32_16x16x32_bf16(pf[1][c], vf, oacc[1][tt], 0, 0, 0);
            }
        }
    }

    // epilogue: normalize by l (col 64 -> lanes l15==0), write ctx[b][s][h*64+d]
    int b = bh >> 4, h = bh & 15;
#pragma unroll
    for (int mi = 0; mi < 2; mi++) {
        float inv[4];
#pragma unroll
        for (int r = 0; r < 4; r++)
            inv[r] = 1.0f / __shfl(oacc[mi][4][r], lane & 48);
#pragma unroll
        for (int tt = 0; tt < 4; tt++)
#pragma unroll
            for (int r = 0; r < 4; r++) {
                int srow = m0w + mi * 16 + quad * 4 + r;
                ctx[((size_t)(b * S_LEN + srow)) * 1024 + h * 64 + tt * 16 + l15] =
                    f2bf(oacc[mi][tt][r] * inv[r]);
            }
    }
}

extern "C" void kernel_launch(void* const* d_in, const int* in_sizes, int n_in,
                              void* d_out, int out_size, void* d_ws, size_t ws_size,
                              hipStream_t stream) {
    const float* x     = (const float*)d_in[0];
    const float* Wq    = (const float*)d_in[1];
    const float* bq    = (const float*)d_in[2];
    const float* Wk    = (const float*)d_in[3];
    const float* bk    = (const float*)d_in[4];
    const float* Wv    = (const float*)d_in[5];
    const float* bv    = (const float*)d_in[6];
    const float* Wo    = (const float*)d_in[7];
    const float* bo    = (const float*)d_in[8];
    const float* Wp    = (const float*)d_in[9];
    const float* bp    = (const float*)d_in[10];
    const float* alpha = (const float*)d_in[11];
    float* out = (float*)d_out;

    const size_t MB = 1048576;
    char* ws = (char*)d_ws;
    unsigned short* WT   = (unsigned short*)(ws);             // 3072x1024 bf16
    unsigned short* WoT  = (unsigned short*)(ws + 6 * MB);    // 1024x1024 bf16
    unsigned short* xb   = (unsigned short*)(ws + 8 * MB);    // (B,S,D) bf16
    unsigned short* ctx  = (unsigned short*)(ws + 8 * MB);    // aliases xb (dead after QKV)
    unsigned short* Qw   = (unsigned short*)(ws + 16 * MB);   // (B,H,S,dk), pre-scaled
    unsigned short* Kw   = (unsigned short*)(ws + 24 * MB);   // (B,H,S,dk)
    unsigned short* VTg  = (unsigned short*)(ws + 32 * MB);   // (B,H,dk,S)  TRANSPOSED
    float* cosP          = (float*)(ws + 40 * MB);            // (B,H,S) fp32
    float* sinP          = (float*)(ws + 40 * MB + 262144);

    hipLaunchKernelGGL(cvt_x, dim3(2048), dim3(256), 0, stream, x, xb);
    hipLaunchKernelGGL(transpose4, dim3(1024), dim3(256), 0, stream,
                       Wq, Wk, Wv, Wo, WT, WT + 1048576, WT + 2097152, WoT);
    hipLaunchKernelGGL(phase_kernel, dim3(4096), dim3(256), 0, stream,
                       x, Wp, bp, cosP, sinP);
    hipLaunchKernelGGL(gemm_bt, dim3(32, 24), dim3(256), 0, stream,
                       xb, WT, 3072, 1, bq, bk, bv, Qw, Kw, VTg, (float*)nullptr);
    hipLaunchKernelGGL(attn_kernel, dim3(512), dim3(256), 0, stream,
                       Qw, Kw, VTg, cosP, sinP, alpha, ctx);
    hipLaunchKernelGGL(gemm_bt, dim3(32, 8), dim3(256), 0, stream,
                       ctx, WoT, 1024, 0, bo, bo, bo,
                       (unsigned short*)nullptr, (unsigned short*)nullptr,
                       (unsigned short*)nullptr, out);
}